// Round 1
// baseline (38.765 us; speedup 1.0000x reference)
//
#include <hip/hip_runtime.h>
#include <cstddef>

// out[e,j] = tanh( A[row[e],j] + B[col[e],j] )
// A[n] = W0·(x[n,0:64]+x[n,128:192]) + W1·x[n,64:128]
// B[n] = W0·x[n,64:128] + W1·(x[n,0:64]+x[n,128:192])
// W0 = W[:, 0:64], W1 = W[:, 64:128], W row-major [9][128].

__device__ __forceinline__ float tanh_fast(float s) {
    s = fminf(fmaxf(s, -30.0f), 30.0f);
    float ex = __expf(2.0f * s);
    return __fdividef(ex - 1.0f, ex + 1.0f);
}

// Kernel 1: per-node projections. 4 lanes (a quad) per node; 64 nodes per 256-thread block.
__global__ __launch_bounds__(256) void node_proj_kernel(
    const float* __restrict__ x, const float* __restrict__ W,
    float* __restrict__ A, float* __restrict__ B, int nnodes)
{
    __shared__ float wl[9 * 128];                 // 4.6 KB
    for (int k = threadIdx.x; k < 9 * 128; k += 256) wl[k] = W[k];
    __syncthreads();

    const int quad = threadIdx.x >> 2;            // 0..63: node within block
    const int q    = threadIdx.x & 3;             // lane within quad
    const int n    = blockIdx.x * 64 + quad;
    if (n >= nnodes) return;

    const float* xr = x + (size_t)n * 192;

    float pa[9], pb[9];
#pragma unroll
    for (int j = 0; j < 9; ++j) { pa[j] = 0.0f; pb[j] = 0.0f; }

#pragma unroll
    for (int ii = 0; ii < 4; ++ii) {
        const int c = 16 * ii + 4 * q;            // this lane's float4 channel offset
        float4 x0 = *(const float4*)(xr + c);
        float4 x1 = *(const float4*)(xr + 64 + c);
        float4 x2 = *(const float4*)(xr + 128 + c);
        float ux = x0.x + x2.x, uy = x0.y + x2.y, uz = x0.z + x2.z, uw = x0.w + x2.w;
#pragma unroll
        for (int j = 0; j < 9; ++j) {
            float4 wa = *(const float4*)(wl + j * 128 + c);
            float4 wb = *(const float4*)(wl + j * 128 + 64 + c);
            // pa = wa·u + wb·v ; pb = wa·v + wb·u   (v = x1)
            pa[j] = fmaf(wa.x, ux,   pa[j]); pa[j] = fmaf(wa.y, uy,   pa[j]);
            pa[j] = fmaf(wa.z, uz,   pa[j]); pa[j] = fmaf(wa.w, uw,   pa[j]);
            pa[j] = fmaf(wb.x, x1.x, pa[j]); pa[j] = fmaf(wb.y, x1.y, pa[j]);
            pa[j] = fmaf(wb.z, x1.z, pa[j]); pa[j] = fmaf(wb.w, x1.w, pa[j]);
            pb[j] = fmaf(wa.x, x1.x, pb[j]); pb[j] = fmaf(wa.y, x1.y, pb[j]);
            pb[j] = fmaf(wa.z, x1.z, pb[j]); pb[j] = fmaf(wa.w, x1.w, pb[j]);
            pb[j] = fmaf(wb.x, ux,   pb[j]); pb[j] = fmaf(wb.y, uy,   pb[j]);
            pb[j] = fmaf(wb.z, uz,   pb[j]); pb[j] = fmaf(wb.w, uw,   pb[j]);
        }
    }

    // quad butterfly reduce: all 4 lanes end with the full 64-channel sums
#pragma unroll
    for (int j = 0; j < 9; ++j) {
        pa[j] += __shfl_xor(pa[j], 1); pa[j] += __shfl_xor(pa[j], 2);
        pb[j] += __shfl_xor(pb[j], 1); pb[j] += __shfl_xor(pb[j], 2);
    }

    float* Ar = A + (size_t)n * 9;
    float* Br = B + (size_t)n * 9;
    for (int j = q; j < 9; j += 4) { Ar[j] = pa[j]; Br[j] = pb[j]; }
}

// Kernel 2: one thread per output element t = e*9 + j. Coalesced writes.
__global__ __launch_bounds__(256) void edge_map_kernel(
    const int* __restrict__ ei, const float* __restrict__ A,
    const float* __restrict__ B, float* __restrict__ out,
    int nedges, int total)
{
    int t = blockIdx.x * 256 + threadIdx.x;
    if (t >= total) return;
    // e = t / 9 via magic multiply (exact for t < 2^31)
    int e = (int)(((long long)t * 954437177LL) >> 33);
    int j = t - e * 9;
    int row = ei[e];
    int col = ei[nedges + e];
    float s = A[row * 9 + j] + B[col * 9 + j];
    out[t] = tanh_fast(s);
}

extern "C" void kernel_launch(void* const* d_in, const int* in_sizes, int n_in,
                              void* d_out, int out_size, void* d_ws, size_t ws_size,
                              hipStream_t stream) {
    const float* x  = (const float*)d_in[0];   // [N, 192] fp32
    const float* W  = (const float*)d_in[1];   // [9, 128] fp32
    const int*   ei = (const int*)d_in[2];     // [2, E] (harness converts ints -> int32)
    float* out = (float*)d_out;                // [E*9] fp32

    const int nnodes = in_sizes[0] / 192;
    const int nedges = in_sizes[2] / 2;

    float* A = (float*)d_ws;                   // [nnodes*9]
    float* B = A + (size_t)nnodes * 9;         // [nnodes*9]  (total 3.6 MB of ws)

    const int blocks1 = (nnodes + 63) / 64;
    node_proj_kernel<<<blocks1, 256, 0, stream>>>(x, W, A, B, nnodes);

    const int total   = nedges * 9;
    const int blocks2 = (total + 255) / 256;
    edge_map_kernel<<<blocks2, 256, 0, stream>>>(ei, A, B, out, nedges, total);
}